// Round 14
// baseline (219.789 us; speedup 1.0000x reference)
//
#include <hip/hip_runtime.h>
#include <hip/hip_bf16.h>
#include <cstdint>
#include <cstddef>

#define NN 100000
#define NE 1600000
#define KD 256
#define OD 128
#define NB 391      // ceil(NN/256) buckets of 256 src nodes
#define CAP 8192    // staging capacity per bucket (mean 6250, sigma ~79)
#define PCAP 9984   // padded CSR region per bucket (CAP + 256*7)
#define NGB 782     // gemm blocks in fused kernel (128 rows each)

typedef __attribute__((ext_vector_type(8))) __bf16 bf16x8;
typedef __attribute__((ext_vector_type(4))) float f32x4;
typedef __attribute__((ext_vector_type(8))) unsigned short ushort8;
typedef __attribute__((ext_vector_type(4))) unsigned int uint32x4;

static __device__ __forceinline__ unsigned short f2bf(float f) {
  return __builtin_bit_cast(unsigned short, (__bf16)f);
}

// ---------------- kernel 1: W -> Wt bf16 transposed; also init bcur ---------------
__global__ void prep_wt_k(const float* __restrict__ W, unsigned short* __restrict__ Wt,
                          int* __restrict__ bcur) {
  const int i = blockIdx.x * 256 + threadIdx.x;  // 32768 total
  const int k = i >> 7;   // 0..255
  const int n = i & 127;  // 0..127
  Wt[n * KD + k] = f2bf(W[i]);
  if (i < NB) bcur[i] = i * CAP;
}

// ---------------- kernel 2: FUSED  gemm (blocks 0..781) | bin (782..1172) ---------
// gemm: 8 waves, 128 rows/block, whole Wt in LDS (XOR-swizzled), MFMA 16x16x32.
//       A-loads per k-step. (Hoisting regressed twice: compiler sinks the 16
//       float4 past the barrier and re-fetches — see R10/R12 post-mortems.)
// bin : 512 thr, 4096 edges/block, LDS bucket-sort by src>>8, append runs to stage.
__global__ __launch_bounds__(512, 4) void fused_k(
    const float* __restrict__ x, const unsigned short* __restrict__ Wt,
    const float* __restrict__ a, unsigned short* __restrict__ h,
    float* __restrict__ ssrc, float* __restrict__ sdst,
    const int* __restrict__ el, int* __restrict__ bcur,
    unsigned* __restrict__ stage) {
  __shared__ alignas(16) char smem[65536];
  const int t = threadIdx.x;

  if (blockIdx.x < NGB) {
    // ------------------------- GEMM part -------------------------
    unsigned short* Bl = (unsigned short*)smem;  // 128 rows x 512 B, swizzled
#pragma unroll
    for (int it = 0; it < 8; ++it) {
      const int c = it * 512 + t;        // 4096 chunks of 16 B
      const int r = c >> 5;
      const int c16 = c & 31;
      const ushort8 v = *(const ushort8*)(Wt + r * 256 + c16 * 8);
      const int byt = (r * 512 + c16 * 16) ^ ((r & 7) << 4);
      *(ushort8*)((char*)Bl + byt) = v;
    }
    const int lane = t & 63;
    const int wave = t >> 6;
    const int col = lane & 15;
    const int kg = lane >> 4;
    const int m0 = blockIdx.x * 128 + wave * 16;
    const int arow = m0 + col;
    const bool rowok = arow < NN;
    const float* __restrict__ xrow = x + (size_t)arow * KD;
    __syncthreads();

    f32x4 acc[8];
#pragma unroll
    for (int i = 0; i < 8; ++i) acc[i] = (f32x4)0.0f;

#pragma unroll
    for (int s = 0; s < 8; ++s) {
      const int kk = s * 32 + kg * 8;
      bf16x8 af = (bf16x8)(__bf16)0.0f;
      if (rowok) {
        const float4 f0 = *(const float4*)(xrow + kk);
        const float4 f1 = *(const float4*)(xrow + kk + 4);
        af[0] = (__bf16)f0.x; af[1] = (__bf16)f0.y; af[2] = (__bf16)f0.z; af[3] = (__bf16)f0.w;
        af[4] = (__bf16)f1.x; af[5] = (__bf16)f1.y; af[6] = (__bf16)f1.z; af[7] = (__bf16)f1.w;
      }
#pragma unroll
      for (int nt = 0; nt < 8; ++nt) {
        const int n = nt * 16 + col;
        const int byt = (n * 512 + s * 64 + kg * 16) ^ ((col & 7) << 4);
        const ushort8 bu = *(const ushort8*)((const char*)Bl + byt);
        const bf16x8 bf = __builtin_bit_cast(bf16x8, bu);
        acc[nt] = __builtin_amdgcn_mfma_f32_16x16x32_bf16(af, bf, acc[nt], 0, 0, 0);
      }
    }

    // C/D layout: col = lane&15, row = (lane>>4)*4 + r
    float ps[4] = {0.f, 0.f, 0.f, 0.f};
    float pd[4] = {0.f, 0.f, 0.f, 0.f};
#pragma unroll
    for (int nt = 0; nt < 8; ++nt) {
      const int n = nt * 16 + col;
      const float av = a[n];
      const float av2 = a[OD + n];
#pragma unroll
      for (int r = 0; r < 4; ++r) {
        const float v = acc[nt][r];
        const int row = m0 + kg * 4 + r;
        if (row < NN) h[(size_t)row * OD + n] = f2bf(v);
        ps[r] += v * av;
        pd[r] += v * av2;
      }
    }
#pragma unroll
    for (int off = 1; off < 16; off <<= 1) {
#pragma unroll
      for (int r = 0; r < 4; ++r) {
        ps[r] += __shfl_xor(ps[r], off, 64);
        pd[r] += __shfl_xor(pd[r], off, 64);
      }
    }
    if (col == 0) {
#pragma unroll
      for (int r = 0; r < 4; ++r) {
        const int row = m0 + kg * 4 + r;
        // pre-scale scores by log2(e): weight pass uses exp2 (leaky commutes w/ scale)
        if (row < NN) {
          ssrc[row] = ps[r] * 1.442695041f;
          sdst[row] = pd[r] * 1.442695041f;
        }
      }
    }
  } else {
    // ------------------------- BIN part -------------------------
    unsigned* sorted = (unsigned*)smem;                       // 16384 B
    unsigned short* bkid = (unsigned short*)(smem + 16384);   // 8192 B
    int* hist  = (int*)(smem + 24576);                        // 392*4
    int* off   = (int*)(smem + 26144);                        // 392*4
    int* cur   = (int*)(smem + 27712);                        // 391*4
    int* delta = (int*)(smem + 29276);                        // 391*4
    const int te = (blockIdx.x - NGB) * 4096 + t * 8;
    int s[8], d[8];
    bool valid[8];
#pragma unroll
    for (int u = 0; u < 8; ++u) valid[u] = (te + u) < NE;
    if (te + 7 < NE) {
      const int4 a0 = *(const int4*)(el + te);
      const int4 a1 = *(const int4*)(el + te + 4);
      const int4 b0 = *(const int4*)(el + NE + te);
      const int4 b1 = *(const int4*)(el + NE + te + 4);
      s[0] = a0.x; s[1] = a0.y; s[2] = a0.z; s[3] = a0.w;
      s[4] = a1.x; s[5] = a1.y; s[6] = a1.z; s[7] = a1.w;
      d[0] = b0.x; d[1] = b0.y; d[2] = b0.z; d[3] = b0.w;
      d[4] = b1.x; d[5] = b1.y; d[6] = b1.z; d[7] = b1.w;
    } else {
#pragma unroll
      for (int u = 0; u < 8; ++u) {
        s[u] = valid[u] ? el[te + u] : 0;
        d[u] = valid[u] ? el[NE + te + u] : 0;
      }
    }
    for (int i = t; i <= NB; i += 512) hist[i] = 0;
    __syncthreads();
#pragma unroll
    for (int u = 0; u < 8; ++u)
      if (valid[u]) atomicAdd(&hist[s[u] >> 8], 1);
    __syncthreads();
    // exclusive scan of hist[0..NB] by wave 0 (7 entries/lane)
    if (t < 64) {
      int v[7];
      int sum = 0;
#pragma unroll
      for (int i = 0; i < 7; ++i) {
        const int idx = t * 7 + i;
        v[i] = (idx <= NB) ? hist[idx] : 0;
        sum += v[i];
      }
      int pre = sum;
#pragma unroll
      for (int o = 1; o < 64; o <<= 1) {
        const int nb = __shfl_up(pre, o, 64);
        if (t >= o) pre += nb;
      }
      pre -= sum;  // exclusive across lanes
      int run = pre;
#pragma unroll
      for (int i = 0; i < 7; ++i) {
        const int idx = t * 7 + i;
        if (idx <= NB) off[idx] = run;
        run += v[i];
      }
    }
    __syncthreads();
    for (int i = t; i < NB; i += 512) cur[i] = off[i];
    __syncthreads();
#pragma unroll
    for (int u = 0; u < 8; ++u)
      if (valid[u]) {
        const int b = s[u] >> 8;
        const int p = atomicAdd(&cur[b], 1);
        sorted[p] = ((unsigned)(s[u] & 255) << 17) | (unsigned)d[u];
        bkid[p] = (unsigned short)b;
      }
    __syncthreads();
    for (int b = t; b < NB; b += 512) {
      const int len = off[b + 1] - off[b];
      if (len > 0) {
        const int gb = atomicAdd(&bcur[b], len);
        delta[b] = gb - off[b];
      }
    }
    __syncthreads();
    const int n = off[NB];
    for (int i = t; i < n; i += 512) {
      const int b = bkid[i];
      const int pos = delta[b] + i;
      if (pos < (b + 1) * CAP) stage[pos] = sorted[i];  // overflow clamp (never hit)
    }
  }
}

// ---------------- kernel 3: per-bucket LDS hist/scan + weight + padded place ------
// CSR region per bucket is fixed: [b*PCAP, (b+1)*PCAP). Each node's run is padded
// to a multiple of 8 with {w=0, dst=first dst of run} so aggr has no bounds logic.
// entry = (bf15(exp2(leaky(ssrc[s]+sdst[d])))<<17) | dst   (w>0 -> 15 bits suffice)
__global__ __launch_bounds__(256) void place2_k(const unsigned* __restrict__ stage,
                                                const int* __restrict__ bcur,
                                                const float* __restrict__ ssrc,
                                                const float* __restrict__ sdst,
                                                unsigned* __restrict__ csrw,
                                                uint2* __restrict__ rc) {
  __shared__ unsigned ebuf[CAP];   // 32 KB
  __shared__ float sl[256];
  __shared__ int hist2[256];
  __shared__ int exc[256];
  __shared__ int cur2[256];
  __shared__ unsigned firstd[256];
  const int b = blockIdx.x;
  const int t = threadIdx.x;
  const int node = b * 256 + t;
  const int base = b * PCAP;
  int tot = bcur[b] - b * CAP;
  tot = tot > CAP ? CAP : tot;
  hist2[t] = 0;
  sl[t] = (node < NN) ? ssrc[node] : 0.f;
  for (int i = t; i < tot; i += 256) ebuf[i] = stage[(size_t)b * CAP + i];
  __syncthreads();
  for (int i = t; i < tot; i += 256) atomicAdd(&hist2[ebuf[i] >> 17], 1);
  __syncthreads();
  // exclusive scan of PADDED counts by wave 0 (4/lane)
  if (t < 64) {
    int p[4];
    int sum = 0;
#pragma unroll
    for (int i = 0; i < 4; ++i) {
      const int c = hist2[t * 4 + i];
      p[i] = (c + 7) & ~7;  // 0 stays 0
      sum += p[i];
    }
    int pre = sum;
#pragma unroll
    for (int o = 1; o < 64; o <<= 1) {
      const int nb = __shfl_up(pre, o, 64);
      if (t >= o) pre += nb;
    }
    pre -= sum;
    int run = pre;
#pragma unroll
    for (int i = 0; i < 4; ++i) { exc[t * 4 + i] = run; run += p[i]; }
  }
  __syncthreads();
  const int c = hist2[t];
  const int pc = (c + 7) & ~7;
  if (node < NN) rc[node] = make_uint2((unsigned)pc, (unsigned)(base + exc[t]));
  cur2[t] = exc[t];
  __syncthreads();
  for (int i = t; i < tot; i += 256) {
    const unsigned u = ebuf[i];
    const int s = u >> 17;
    const unsigned d = u & 0x1ffffu;
    const float sv = sl[s] + sdst[d];                 // log2-domain score
    const float w = exp2f(fmaxf(sv, 0.2f * sv));      // leaky+exp, w > 0
    unsigned wb = __builtin_bit_cast(unsigned, w);
    wb += 0x7fffu + ((wb >> 16) & 1u);                // round-to-nearest bf16
    const unsigned ent = ((wb >> 16) << 17) | d;      // sign bit is 0 -> 15 bits
    const int p = atomicAdd(&cur2[s], 1);
    if (p == exc[s]) firstd[s] = d;                   // capture a hot pad target
    csrw[base + p] = ent;
  }
  __syncthreads();
  // pad each run to multiple of 8 with {w=0, dst=firstd} (row stays L1/L2-hot)
  if (c > 0) {
    const unsigned padent = firstd[t];                // weight bits = 0 -> w = 0.0f
    const int e0 = exc[t];
    for (int i = c; i < pc; ++i) csrw[base + e0 + i] = padent;
  }
}

// ---------------- kernel 4: wave-per-node aggregate, full-depth prefetch ----------
// lane-group g = lane>>4 handles edge slot g; lane sub = lane&15 covers cols sub*8..+7
// nit <= 5 covers ~all nodes: issue ALL csr loads, then ALL row gathers, then a
// single volatile asm consuming every gathered value — the compiler CANNOT sink
// the loads back into the compute chain (R13's compile did exactly that, VGPR 36).
__global__ __launch_bounds__(256) void aggr_k(
    const unsigned short* __restrict__ h, const unsigned* __restrict__ csrw,
    const uint2* __restrict__ rc, float* __restrict__ out) {
  const int lane = threadIdx.x & 63;
  const int g = lane >> 4;
  const int sub = lane & 15;
  const int node = blockIdx.x * 4 + (threadIdx.x >> 6);  // grid covers exactly NN
  const uint2 rcv = rc[node];
  const int pdeg = (int)rcv.x;                 // padded degree (multiple of 8)
  const int r0 = (int)rcv.y;
  const uint32x4* __restrict__ hp = (const uint32x4*)h;  // one h row = 16 uint32x4
  float acc[8] = {0.f, 0.f, 0.f, 0.f, 0.f, 0.f, 0.f, 0.f};
  float sw = 0.f;
  const unsigned losel = 0x05040100u;   // [e0.lo16 | e1.lo16]
  const unsigned hisel = 0x07060302u;   // [e0.hi16 | e1.hi16]
  const unsigned onepk = 0x3F803F80u;   // packed bf16 (1.0, 1.0)
  const int nit = pdeg >> 3;            // 8 edges per iteration (4 groups x 2 slots)
  const int nit0 = nit > 5 ? 5 : nit;

  unsigned ua[5] = {0, 0, 0, 0, 0}, ub[5] = {0, 0, 0, 0, 0};
  uint32x4 qa[5] = {}, qb[5] = {};
#pragma unroll
  for (int s = 0; s < 5; ++s)
    if (s < nit0) {
      const int j = r0 + s * 8 + g;
      ua[s] = csrw[j];
      ub[s] = csrw[j + 4];
    }
#pragma unroll
  for (int s = 0; s < 5; ++s)
    if (s < nit0) {
      qa[s] = hp[(ua[s] & 0x1ffffu) * 16u + sub];
      qb[s] = hp[(ub[s] & 0x1ffffu) * 16u + sub];
    }
  // single barrier asm: every gathered value is an operand -> all 10 row-gathers
  // must be issued & resident before ANY compute below can be scheduled.
  asm volatile("" : "+v"(qa[0]), "+v"(qa[1]), "+v"(qa[2]), "+v"(qa[3]), "+v"(qa[4]),
                    "+v"(qb[0]), "+v"(qb[1]), "+v"(qb[2]), "+v"(qb[3]), "+v"(qb[4]));
#pragma unroll
  for (int s = 0; s < 5; ++s)
    if (s < nit0) {
      const unsigned wpk = (ua[s] >> 17) | ((ub[s] >> 17) << 16);  // bf16 (w0,w1)
      asm("v_dot2_f32_bf16 %0, %1, %2, %0" : "+v"(sw) : "v"(wpk), "v"(onepk));
      const unsigned k0a[4] = {qa[s][0], qa[s][1], qa[s][2], qa[s][3]};
      const unsigned k1a[4] = {qb[s][0], qb[s][1], qb[s][2], qb[s][3]};
#pragma unroll
      for (int q = 0; q < 4; ++q) {
        const unsigned lo = __builtin_amdgcn_perm(k1a[q], k0a[q], losel);
        const unsigned hi = __builtin_amdgcn_perm(k1a[q], k0a[q], hisel);
        asm("v_dot2_f32_bf16 %0, %1, %2, %0" : "+v"(acc[q * 2]) : "v"(wpk), "v"(lo));
        asm("v_dot2_f32_bf16 %0, %1, %2, %0" : "+v"(acc[q * 2 + 1]) : "v"(wpk), "v"(hi));
      }
    }
  // rare tail (deg > 40): simple non-pipelined loop
  for (int it = 5; it < nit; ++it) {
    const int j = r0 + it * 8 + g;
    const unsigned u0 = csrw[j];
    const unsigned u1 = csrw[j + 4];
    const uint32x4 p0 = hp[(u0 & 0x1ffffu) * 16u + sub];
    const uint32x4 p1 = hp[(u1 & 0x1ffffu) * 16u + sub];
    const unsigned wpk = (u0 >> 17) | ((u1 >> 17) << 16);
    asm("v_dot2_f32_bf16 %0, %1, %2, %0" : "+v"(sw) : "v"(wpk), "v"(onepk));
    const unsigned k0a[4] = {p0[0], p0[1], p0[2], p0[3]};
    const unsigned k1a[4] = {p1[0], p1[1], p1[2], p1[3]};
#pragma unroll
    for (int q = 0; q < 4; ++q) {
      const unsigned lo = __builtin_amdgcn_perm(k1a[q], k0a[q], losel);
      const unsigned hi = __builtin_amdgcn_perm(k1a[q], k0a[q], hisel);
      asm("v_dot2_f32_bf16 %0, %1, %2, %0" : "+v"(acc[q * 2]) : "v"(wpk), "v"(lo));
      asm("v_dot2_f32_bf16 %0, %1, %2, %0" : "+v"(acc[q * 2 + 1]) : "v"(wpk), "v"(hi));
    }
  }
  // reduce across the 4 edge-groups (same sub = same columns)
#pragma unroll
  for (int off = 16; off < 64; off <<= 1) {
    sw += __shfl_xor(sw, off, 64);
#pragma unroll
    for (int q = 0; q < 8; ++q) acc[q] += __shfl_xor(acc[q], off, 64);
  }
  const float inv = pdeg > 0 ? 1.0f / sw : 0.f;
  float o[8];
#pragma unroll
  for (int q = 0; q < 8; ++q) {
    const float v = acc[q] * inv;
    o[q] = v > 0.f ? v : __expf(v) - 1.f;  // elu alpha=1
  }
  if (lane < 16) {
    float4* op = (float4*)(out + (size_t)node * OD + sub * 8);
    op[0] = make_float4(o[0], o[1], o[2], o[3]);
    op[1] = make_float4(o[4], o[5], o[6], o[7]);
  }
}

extern "C" void kernel_launch(void* const* d_in, const int* in_sizes, int n_in,
                              void* d_out, int out_size, void* d_ws, size_t ws_size,
                              hipStream_t stream) {
  const float* x = (const float*)d_in[0];
  const int* el = (const int*)d_in[1];
  const float* W = (const float*)d_in[2];
  const float* a = (const float*)d_in[3];
  float* out = (float*)d_out;
  char* ws = (char*)d_ws;

  const size_t S = 400384;  // 100000*4 padded to 512
  float* ssrc    = (float*)(ws + 0 * S);
  float* sdst    = (float*)(ws + 1 * S);
  uint2* rc      = (uint2*)(ws + 2 * S);        // 800 KB (spans slots 2+3)
  int* bcur      = (int*)(ws + 4 * S);          // 391 ints
  unsigned short* Wt = (unsigned short*)(ws + 4 * S + 8192);          // 64 KB
  unsigned short* h  = (unsigned short*)(ws + 4 * S + 8192 + 65536);  // 25.6 MB
  unsigned* csrw = (unsigned*)(ws + 4 * S + 8192 + 65536 + (size_t)NN * OD * 2);  // 15.6 MB
  // staging (12.81 MB) lives in d_out scratch space (51.2 MB); consumed by
  // place2_k before aggr_k rewrites every output element.
  unsigned* stage = (unsigned*)d_out;

  prep_wt_k<<<128, 256, 0, stream>>>(W, Wt, bcur);
  fused_k<<<NGB + NB, 512, 0, stream>>>(x, Wt, a, h, ssrc, sdst, el, bcur, stage);
  place2_k<<<NB, 256, 0, stream>>>(stage, bcur, ssrc, sdst, csrw, rc);
  aggr_k<<<NN / 4, 256, 0, stream>>>(h, csrw, rc, out);
}

// Round 15
// 123.719 us; speedup vs baseline: 1.7765x; 1.7765x over previous
//
#include <hip/hip_runtime.h>
#include <hip/hip_bf16.h>
#include <cstdint>
#include <cstddef>

#define NN 100000
#define NE 1600000
#define KD 256
#define OD 128
#define NB 782      // buckets of 128 src nodes (ceil(100000/128))
#define CAP 2560    // staging capacity per bucket (mean 2048, sigma ~45 -> 11 sigma)
#define PCAPL 3456  // padded LDS CSR capacity (CAP + 128*7, hard upper bound)
#define NGB 782     // gemm blocks in fused kernel (128 rows each)

typedef __attribute__((ext_vector_type(8))) __bf16 bf16x8;
typedef __attribute__((ext_vector_type(4))) float f32x4;
typedef __attribute__((ext_vector_type(8))) unsigned short ushort8;

static __device__ __forceinline__ unsigned short f2bf(float f) {
  return __builtin_bit_cast(unsigned short, (__bf16)f);
}

// ---------------- kernel 1: W -> Wt bf16 transposed; also init bcur ---------------
__global__ void prep_wt_k(const float* __restrict__ W, unsigned short* __restrict__ Wt,
                          int* __restrict__ bcur) {
  const int i = blockIdx.x * 256 + threadIdx.x;  // 32768 total
  const int k = i >> 7;   // 0..255
  const int n = i & 127;  // 0..127
  Wt[n * KD + k] = f2bf(W[i]);
  if (i < NB) bcur[i] = i * CAP;
}

// ---------------- kernel 2: FUSED  gemm (blocks 0..781) | bin (782..1563) ---------
// gemm: 8 waves, 128 rows/block, whole Wt in LDS (XOR-swizzled), MFMA 16x16x32.
//       A-loads per k-step (hoisting regressed twice — R10/R12 post-mortems).
// bin : 512 thr, 4096 edges/block, LDS bucket-sort by src>>7, append runs to stage.
__global__ __launch_bounds__(512, 4) void fused_k(
    const float* __restrict__ x, const unsigned short* __restrict__ Wt,
    const float* __restrict__ a, unsigned short* __restrict__ h,
    float* __restrict__ ssrc, float* __restrict__ sdst,
    const int* __restrict__ el, int* __restrict__ bcur,
    unsigned* __restrict__ stage) {
  __shared__ alignas(16) char smem[65536];
  const int t = threadIdx.x;

  if (blockIdx.x < NGB) {
    // ------------------------- GEMM part -------------------------
    unsigned short* Bl = (unsigned short*)smem;  // 128 rows x 512 B, swizzled
#pragma unroll
    for (int it = 0; it < 8; ++it) {
      const int c = it * 512 + t;        // 4096 chunks of 16 B
      const int r = c >> 5;
      const int c16 = c & 31;
      const ushort8 v = *(const ushort8*)(Wt + r * 256 + c16 * 8);
      const int byt = (r * 512 + c16 * 16) ^ ((r & 7) << 4);
      *(ushort8*)((char*)Bl + byt) = v;
    }
    const int lane = t & 63;
    const int wave = t >> 6;
    const int col = lane & 15;
    const int kg = lane >> 4;
    const int m0 = blockIdx.x * 128 + wave * 16;
    const int arow = m0 + col;
    const bool rowok = arow < NN;
    const float* __restrict__ xrow = x + (size_t)arow * KD;
    __syncthreads();

    f32x4 acc[8];
#pragma unroll
    for (int i = 0; i < 8; ++i) acc[i] = (f32x4)0.0f;

#pragma unroll
    for (int s = 0; s < 8; ++s) {
      const int kk = s * 32 + kg * 8;
      bf16x8 af = (bf16x8)(__bf16)0.0f;
      if (rowok) {
        const float4 f0 = *(const float4*)(xrow + kk);
        const float4 f1 = *(const float4*)(xrow + kk + 4);
        af[0] = (__bf16)f0.x; af[1] = (__bf16)f0.y; af[2] = (__bf16)f0.z; af[3] = (__bf16)f0.w;
        af[4] = (__bf16)f1.x; af[5] = (__bf16)f1.y; af[6] = (__bf16)f1.z; af[7] = (__bf16)f1.w;
      }
#pragma unroll
      for (int nt = 0; nt < 8; ++nt) {
        const int n = nt * 16 + col;
        const int byt = (n * 512 + s * 64 + kg * 16) ^ ((col & 7) << 4);
        const ushort8 bu = *(const ushort8*)((const char*)Bl + byt);
        const bf16x8 bf = __builtin_bit_cast(bf16x8, bu);
        acc[nt] = __builtin_amdgcn_mfma_f32_16x16x32_bf16(af, bf, acc[nt], 0, 0, 0);
      }
    }

    // C/D layout: col = lane&15, row = (lane>>4)*4 + r
    float ps[4] = {0.f, 0.f, 0.f, 0.f};
    float pd[4] = {0.f, 0.f, 0.f, 0.f};
#pragma unroll
    for (int nt = 0; nt < 8; ++nt) {
      const int n = nt * 16 + col;
      const float av = a[n];
      const float av2 = a[OD + n];
#pragma unroll
      for (int r = 0; r < 4; ++r) {
        const float v = acc[nt][r];
        const int row = m0 + kg * 4 + r;
        if (row < NN) h[(size_t)row * OD + n] = f2bf(v);
        ps[r] += v * av;
        pd[r] += v * av2;
      }
    }
#pragma unroll
    for (int off = 1; off < 16; off <<= 1) {
#pragma unroll
      for (int r = 0; r < 4; ++r) {
        ps[r] += __shfl_xor(ps[r], off, 64);
        pd[r] += __shfl_xor(pd[r], off, 64);
      }
    }
    if (col == 0) {
#pragma unroll
      for (int r = 0; r < 4; ++r) {
        const int row = m0 + kg * 4 + r;
        // pre-scale scores by log2(e): weight pass uses exp2 (leaky commutes w/ scale)
        if (row < NN) {
          ssrc[row] = ps[r] * 1.442695041f;
          sdst[row] = pd[r] * 1.442695041f;
        }
      }
    }
  } else {
    // ------------------------- BIN part -------------------------
    unsigned* sorted = (unsigned*)smem;                       // 16384 B
    unsigned short* bkid = (unsigned short*)(smem + 16384);   // 8192 B
    int* hist  = (int*)(smem + 24576);                        // 783*4 -> 3136
    int* off   = (int*)(smem + 27712);                        // 3136
    int* cur   = (int*)(smem + 30848);                        // 3136
    int* delta = (int*)(smem + 33984);                        // 3136 (end 37120)
    const int te = (blockIdx.x - NGB) * 4096 + t * 8;
    int s[8], d[8];
    bool valid[8];
#pragma unroll
    for (int u = 0; u < 8; ++u) valid[u] = (te + u) < NE;
    if (te + 7 < NE) {
      const int4 a0 = *(const int4*)(el + te);
      const int4 a1 = *(const int4*)(el + te + 4);
      const int4 b0 = *(const int4*)(el + NE + te);
      const int4 b1 = *(const int4*)(el + NE + te + 4);
      s[0] = a0.x; s[1] = a0.y; s[2] = a0.z; s[3] = a0.w;
      s[4] = a1.x; s[5] = a1.y; s[6] = a1.z; s[7] = a1.w;
      d[0] = b0.x; d[1] = b0.y; d[2] = b0.z; d[3] = b0.w;
      d[4] = b1.x; d[5] = b1.y; d[6] = b1.z; d[7] = b1.w;
    } else {
#pragma unroll
      for (int u = 0; u < 8; ++u) {
        s[u] = valid[u] ? el[te + u] : 0;
        d[u] = valid[u] ? el[NE + te + u] : 0;
      }
    }
    for (int i = t; i <= NB; i += 512) hist[i] = 0;
    __syncthreads();
#pragma unroll
    for (int u = 0; u < 8; ++u)
      if (valid[u]) atomicAdd(&hist[s[u] >> 7], 1);
    __syncthreads();
    // exclusive scan of hist[0..NB] by wave 0 (13 entries/lane)
    if (t < 64) {
      int v[13];
      int sum = 0;
#pragma unroll
      for (int i = 0; i < 13; ++i) {
        const int idx = t * 13 + i;
        v[i] = (idx <= NB) ? hist[idx] : 0;
        sum += v[i];
      }
      int pre = sum;
#pragma unroll
      for (int o = 1; o < 64; o <<= 1) {
        const int nb = __shfl_up(pre, o, 64);
        if (t >= o) pre += nb;
      }
      pre -= sum;  // exclusive across lanes
      int run = pre;
#pragma unroll
      for (int i = 0; i < 13; ++i) {
        const int idx = t * 13 + i;
        if (idx <= NB) off[idx] = run;
        run += v[i];
      }
    }
    __syncthreads();
    for (int i = t; i < NB; i += 512) cur[i] = off[i];
    __syncthreads();
#pragma unroll
    for (int u = 0; u < 8; ++u)
      if (valid[u]) {
        const int b = s[u] >> 7;
        const int p = atomicAdd(&cur[b], 1);
        sorted[p] = ((unsigned)(s[u] & 127) << 17) | (unsigned)d[u];
        bkid[p] = (unsigned short)b;
      }
    __syncthreads();
    for (int b = t; b < NB; b += 512) {
      const int len = off[b + 1] - off[b];
      if (len > 0) {
        const int gb = atomicAdd(&bcur[b], len);
        delta[b] = gb - off[b];
      }
    }
    __syncthreads();
    const int n = off[NB];
    for (int i = t; i < n; i += 512) {
      const int b = bkid[i];
      const int pos = delta[b] + i;
      if (pos < (b + 1) * CAP) stage[pos] = sorted[i];  // overflow clamp (never hit)
    }
  }
}

// ---------------- kernel 3: FUSED place+aggr, one 512-thr block per 128-node bucket
// Phase 1 (place): LDS hist/scan, per-edge weight, padded CSR built ENTIRELY in LDS
//   entry = (bf15(exp2(leaky(ssrc[s]+sdst[d])))<<17) | dst  (w>0 -> 15 bits suffice)
// Phase 2 (aggr): 8 waves x 16 nodes; per node the proven dot2 loop reads the CSR
//   from LDS (no global csrw round-trip). 4 blocks/CU (27 KB LDS) = 100% occupancy;
//   all 782 blocks co-resident -> no tail.
__global__ __launch_bounds__(512, 4) void paggr_k(
    const unsigned* __restrict__ stage, const int* __restrict__ bcur,
    const float* __restrict__ ssrc, const float* __restrict__ sdst,
    const unsigned short* __restrict__ h, float* __restrict__ out) {
  __shared__ unsigned ebuf[CAP];      // 10.0 KB
  __shared__ unsigned csrl[PCAPL];    // 13.5 KB
  __shared__ float sl[128];
  __shared__ int hist2[128];
  __shared__ int exc[128];
  __shared__ int cur2[128];
  __shared__ unsigned firstd[128];
  __shared__ unsigned short pdegs[128];
  const int b = blockIdx.x;
  const int t = threadIdx.x;
  int tot = bcur[b] - b * CAP;
  tot = tot > CAP ? CAP : tot;
  if (t < 128) {
    hist2[t] = 0;
    const int node = b * 128 + t;
    sl[t] = (node < NN) ? ssrc[node] : 0.f;
  }
  for (int i = t; i < tot; i += 512) ebuf[i] = stage[(size_t)b * CAP + i];
  __syncthreads();
  for (int i = t; i < tot; i += 512) atomicAdd(&hist2[ebuf[i] >> 17], 1);
  __syncthreads();
  // exclusive scan of PADDED counts (pad to mult of 8), wave 0, 2/lane
  if (t < 64) {
    const int p0 = (hist2[t * 2] + 7) & ~7;      // 0 stays 0
    const int p1 = (hist2[t * 2 + 1] + 7) & ~7;
    const int sum = p0 + p1;
    int pre = sum;
#pragma unroll
    for (int o = 1; o < 64; o <<= 1) {
      const int nb = __shfl_up(pre, o, 64);
      if (t >= o) pre += nb;
    }
    pre -= sum;
    exc[t * 2] = pre;
    exc[t * 2 + 1] = pre + p0;
  }
  __syncthreads();
  if (t < 128) {
    cur2[t] = exc[t];
    pdegs[t] = (unsigned short)((hist2[t] + 7) & ~7);
  }
  __syncthreads();
  for (int i = t; i < tot; i += 512) {
    const unsigned u = ebuf[i];
    const int s = u >> 17;
    const unsigned d = u & 0x1ffffu;
    const float sv = sl[s] + sdst[d];                 // log2-domain score
    const float w = exp2f(fmaxf(sv, 0.2f * sv));      // leaky+exp, w > 0
    unsigned wb = __builtin_bit_cast(unsigned, w);
    wb += 0x7fffu + ((wb >> 16) & 1u);                // round-to-nearest bf16
    const int p = atomicAdd(&cur2[s], 1);
    if (p == exc[s]) firstd[s] = d;                   // hot pad target
    csrl[p] = ((wb >> 16) << 17) | d;
  }
  __syncthreads();
  // pad each run to multiple of 8 with {w=0, dst=firstd}
  if (t < 128) {
    const int c = hist2[t];
    const int pc = pdegs[t];
    if (c > 0) {
      const unsigned padent = firstd[t];              // weight bits = 0 -> w = 0.0f
      const int e0 = exc[t];
      for (int i = c; i < pc; ++i) csrl[e0 + i] = padent;
    }
  }
  __syncthreads();
  // ------------- phase 2: aggregation, 8 waves x 16 nodes -------------
  const int lane = t & 63;
  const int wave = t >> 6;
  const int g = lane >> 4;
  const int sub = lane & 15;
  const uint4* __restrict__ hp = (const uint4*)h;     // one h row = 16 uint4
  const unsigned losel = 0x05040100u;   // [e0.lo16 | e1.lo16]
  const unsigned hisel = 0x07060302u;   // [e0.hi16 | e1.hi16]
  const unsigned onepk = 0x3F803F80u;   // packed bf16 (1.0, 1.0)
  for (int k = 0; k < 16; ++k) {
    const int ln = wave * 16 + k;                     // local node 0..127
    const int node = b * 128 + ln;
    if (node >= NN) break;                            // only trailing nodes invalid
    const int pdeg = pdegs[ln];
    const int r0 = exc[ln];
    float acc[8] = {0.f, 0.f, 0.f, 0.f, 0.f, 0.f, 0.f, 0.f};
    float sw = 0.f;
    const int nit = pdeg >> 3;                        // 8 edges/iter (4 groups x 2)
    int j = r0 + g;
    for (int it = 0; it < nit; ++it, j += 8) {
      const unsigned u0 = csrl[j];
      const unsigned u1 = csrl[j + 4];
      const uint4 p0 = hp[(u0 & 0x1ffffu) * 16u + sub];
      const uint4 p1 = hp[(u1 & 0x1ffffu) * 16u + sub];
      const unsigned wpk = (u0 >> 17) | ((u1 >> 17) << 16);  // bf16 pair (w0,w1)
      asm("v_dot2_f32_bf16 %0, %1, %2, %0" : "+v"(sw) : "v"(wpk), "v"(onepk));
      const unsigned k0a[4] = {p0.x, p0.y, p0.z, p0.w};
      const unsigned k1a[4] = {p1.x, p1.y, p1.z, p1.w};
#pragma unroll
      for (int q = 0; q < 4; ++q) {
        const unsigned lo = __builtin_amdgcn_perm(k1a[q], k0a[q], losel);
        const unsigned hi = __builtin_amdgcn_perm(k1a[q], k0a[q], hisel);
        asm("v_dot2_f32_bf16 %0, %1, %2, %0" : "+v"(acc[q * 2]) : "v"(wpk), "v"(lo));
        asm("v_dot2_f32_bf16 %0, %1, %2, %0" : "+v"(acc[q * 2 + 1]) : "v"(wpk), "v"(hi));
      }
    }
    // reduce across the 4 edge-groups (same sub = same columns)
#pragma unroll
    for (int off = 16; off < 64; off <<= 1) {
      sw += __shfl_xor(sw, off, 64);
#pragma unroll
      for (int q = 0; q < 8; ++q) acc[q] += __shfl_xor(acc[q], off, 64);
    }
    const float inv = pdeg > 0 ? 1.0f / sw : 0.f;
    float o[8];
#pragma unroll
    for (int q = 0; q < 8; ++q) {
      const float v = acc[q] * inv;
      o[q] = v > 0.f ? v : __expf(v) - 1.f;  // elu alpha=1
    }
    if (lane < 16) {
      float4* op = (float4*)(out + (size_t)node * OD + sub * 8);
      op[0] = make_float4(o[0], o[1], o[2], o[3]);
      op[1] = make_float4(o[4], o[5], o[6], o[7]);
    }
  }
}

extern "C" void kernel_launch(void* const* d_in, const int* in_sizes, int n_in,
                              void* d_out, int out_size, void* d_ws, size_t ws_size,
                              hipStream_t stream) {
  const float* x = (const float*)d_in[0];
  const int* el = (const int*)d_in[1];
  const float* W = (const float*)d_in[2];
  const float* a = (const float*)d_in[3];
  float* out = (float*)d_out;
  char* ws = (char*)d_ws;

  const size_t S = 400384;  // 100000*4 padded to 512
  float* ssrc    = (float*)(ws + 0 * S);
  float* sdst    = (float*)(ws + 1 * S);
  int* bcur      = (int*)(ws + 2 * S);          // 782 ints
  unsigned short* Wt = (unsigned short*)(ws + 2 * S + 8192);          // 64 KB
  unsigned short* h  = (unsigned short*)(ws + 2 * S + 8192 + 65536);  // 25.6 MB
  unsigned* stage = (unsigned*)(ws + 2 * S + 8192 + 65536 + (size_t)NN * OD * 2);  // 8.0 MB
  // total ws ~= 35 MB (was 43 MB in R13 — csrw/rc dropped; stage moved out of
  // d_out because paggr now writes out while other blocks still read stage)

  prep_wt_k<<<128, 256, 0, stream>>>(W, Wt, bcur);
  fused_k<<<NGB + NB, 512, 0, stream>>>(x, Wt, a, h, ssrc, sdst, el, bcur, stage);
  paggr_k<<<NB, 512, 0, stream>>>(stage, bcur, ssrc, sdst, h, out);
}

// Round 16
// 116.834 us; speedup vs baseline: 1.8812x; 1.0589x over previous
//
#include <hip/hip_runtime.h>
#include <hip/hip_bf16.h>
#include <cstdint>
#include <cstddef>

#define NN 100000
#define NE 1600000
#define KD 256
#define OD 128
#define NB 391      // ceil(NN/256) buckets of 256 src nodes (place/aggr CSR)
#define CAP 8192    // staging capacity per bucket (mean 6250, sigma ~79)
#define PCAP 9984   // padded CSR region per bucket (CAP + 256*7)
#define NGB 391     // gemm blocks in fused kernel (256 rows each, 1024 thr)
#define NBIN 391    // bin blocks (4096 edges each, 1024 thr)

typedef __attribute__((ext_vector_type(8))) __bf16 bf16x8;
typedef __attribute__((ext_vector_type(4))) float f32x4;
typedef __attribute__((ext_vector_type(8))) unsigned short ushort8;

static __device__ __forceinline__ unsigned short f2bf(float f) {
  return __builtin_bit_cast(unsigned short, (__bf16)f);
}

// ---------------- kernel 1: W -> Wt bf16 transposed; also init bcur ---------------
__global__ void prep_wt_k(const float* __restrict__ W, unsigned short* __restrict__ Wt,
                          int* __restrict__ bcur) {
  const int i = blockIdx.x * 256 + threadIdx.x;  // 32768 total
  const int k = i >> 7;   // 0..255
  const int n = i & 127;  // 0..127
  Wt[n * KD + k] = f2bf(W[i]);
  if (i < NB) bcur[i] = i * CAP;
}

// ---------------- kernel 2: FUSED  gemm (blocks 0..390) | bin (391..781) ----------
// gemm: 1024 thr = 16 waves, 256 rows/block, whole Wt in LDS (XOR-swizzled),
//       MFMA 16x16x32. 2 blocks/CU (64KB LDS) x 16 waves = 32 waves/CU = 100%
//       theoretical occupancy (R15's 512-thr variant capped at 50% -> 33% meas).
// bin : 1024 thr, 4 edges/thread = 4096 edges/block, LDS bucket-sort by src>>8.
__global__ __launch_bounds__(1024, 8) void fused_k(
    const float* __restrict__ x, const unsigned short* __restrict__ Wt,
    const float* __restrict__ a, unsigned short* __restrict__ h,
    float* __restrict__ ssrc, float* __restrict__ sdst,
    const int* __restrict__ el, int* __restrict__ bcur,
    unsigned* __restrict__ stage) {
  __shared__ alignas(16) char smem[65536];
  const int t = threadIdx.x;

  if (blockIdx.x < NGB) {
    // ------------------------- GEMM part -------------------------
    unsigned short* Bl = (unsigned short*)smem;  // 128 rows x 512 B, swizzled
#pragma unroll
    for (int it = 0; it < 4; ++it) {
      const int c = it * 1024 + t;       // 4096 chunks of 16 B
      const int r = c >> 5;
      const int c16 = c & 31;
      const ushort8 v = *(const ushort8*)(Wt + r * 256 + c16 * 8);
      const int byt = (r * 512 + c16 * 16) ^ ((r & 7) << 4);
      *(ushort8*)((char*)Bl + byt) = v;
    }
    const int lane = t & 63;
    const int wave = t >> 6;             // 0..15
    const int col = lane & 15;
    const int kg = lane >> 4;
    const int m0 = blockIdx.x * 256 + wave * 16;
    const int arow = m0 + col;
    const bool rowok = arow < NN;
    const float* __restrict__ xrow = x + (size_t)arow * KD;
    __syncthreads();

    f32x4 acc[8];
#pragma unroll
    for (int i = 0; i < 8; ++i) acc[i] = (f32x4)0.0f;

#pragma unroll
    for (int s = 0; s < 8; ++s) {
      const int kk = s * 32 + kg * 8;
      bf16x8 af = (bf16x8)(__bf16)0.0f;
      if (rowok) {
        const float4 f0 = *(const float4*)(xrow + kk);
        const float4 f1 = *(const float4*)(xrow + kk + 4);
        af[0] = (__bf16)f0.x; af[1] = (__bf16)f0.y; af[2] = (__bf16)f0.z; af[3] = (__bf16)f0.w;
        af[4] = (__bf16)f1.x; af[5] = (__bf16)f1.y; af[6] = (__bf16)f1.z; af[7] = (__bf16)f1.w;
      }
#pragma unroll
      for (int nt = 0; nt < 8; ++nt) {
        const int n = nt * 16 + col;
        const int byt = (n * 512 + s * 64 + kg * 16) ^ ((col & 7) << 4);
        const ushort8 bu = *(const ushort8*)((const char*)Bl + byt);
        const bf16x8 bf = __builtin_bit_cast(bf16x8, bu);
        acc[nt] = __builtin_amdgcn_mfma_f32_16x16x32_bf16(af, bf, acc[nt], 0, 0, 0);
      }
    }

    // C/D layout: col = lane&15, row = (lane>>4)*4 + r
    float ps[4] = {0.f, 0.f, 0.f, 0.f};
    float pd[4] = {0.f, 0.f, 0.f, 0.f};
#pragma unroll
    for (int nt = 0; nt < 8; ++nt) {
      const int n = nt * 16 + col;
      const float av = a[n];
      const float av2 = a[OD + n];
#pragma unroll
      for (int r = 0; r < 4; ++r) {
        const float v = acc[nt][r];
        const int row = m0 + kg * 4 + r;
        if (row < NN) h[(size_t)row * OD + n] = f2bf(v);
        ps[r] += v * av;
        pd[r] += v * av2;
      }
    }
#pragma unroll
    for (int off = 1; off < 16; off <<= 1) {
#pragma unroll
      for (int r = 0; r < 4; ++r) {
        ps[r] += __shfl_xor(ps[r], off, 64);
        pd[r] += __shfl_xor(pd[r], off, 64);
      }
    }
    if (col == 0) {
#pragma unroll
      for (int r = 0; r < 4; ++r) {
        const int row = m0 + kg * 4 + r;
        // pre-scale scores by log2(e): weight pass uses exp2 (leaky commutes w/ scale)
        if (row < NN) {
          ssrc[row] = ps[r] * 1.442695041f;
          sdst[row] = pd[r] * 1.442695041f;
        }
      }
    }
  } else {
    // ------------------------- BIN part -------------------------
    unsigned* sorted = (unsigned*)smem;                       // 16384 B
    unsigned short* bkid = (unsigned short*)(smem + 16384);   // 8192 B
    int* hist  = (int*)(smem + 24576);                        // 392*4
    int* off   = (int*)(smem + 26144);                        // 392*4
    int* cur   = (int*)(smem + 27712);                        // 391*4
    int* delta = (int*)(smem + 29276);                        // 391*4
    const int te = (blockIdx.x - NGB) * 4096 + t * 4;
    int s[4], d[4];
    bool valid[4];
#pragma unroll
    for (int u = 0; u < 4; ++u) valid[u] = (te + u) < NE;
    if (te + 3 < NE) {
      const int4 a0 = *(const int4*)(el + te);
      const int4 b0 = *(const int4*)(el + NE + te);
      s[0] = a0.x; s[1] = a0.y; s[2] = a0.z; s[3] = a0.w;
      d[0] = b0.x; d[1] = b0.y; d[2] = b0.z; d[3] = b0.w;
    } else {
#pragma unroll
      for (int u = 0; u < 4; ++u) {
        s[u] = valid[u] ? el[te + u] : 0;
        d[u] = valid[u] ? el[NE + te + u] : 0;
      }
    }
    for (int i = t; i <= NB; i += 1024) hist[i] = 0;
    __syncthreads();
#pragma unroll
    for (int u = 0; u < 4; ++u)
      if (valid[u]) atomicAdd(&hist[s[u] >> 8], 1);
    __syncthreads();
    // exclusive scan of hist[0..NB] by wave 0 (7 entries/lane)
    if (t < 64) {
      int v[7];
      int sum = 0;
#pragma unroll
      for (int i = 0; i < 7; ++i) {
        const int idx = t * 7 + i;
        v[i] = (idx <= NB) ? hist[idx] : 0;
        sum += v[i];
      }
      int pre = sum;
#pragma unroll
      for (int o = 1; o < 64; o <<= 1) {
        const int nb = __shfl_up(pre, o, 64);
        if (t >= o) pre += nb;
      }
      pre -= sum;  // exclusive across lanes
      int run = pre;
#pragma unroll
      for (int i = 0; i < 7; ++i) {
        const int idx = t * 7 + i;
        if (idx <= NB) off[idx] = run;
        run += v[i];
      }
    }
    __syncthreads();
    for (int i = t; i < NB; i += 1024) cur[i] = off[i];
    __syncthreads();
#pragma unroll
    for (int u = 0; u < 4; ++u)
      if (valid[u]) {
        const int b = s[u] >> 8;
        const int p = atomicAdd(&cur[b], 1);
        sorted[p] = ((unsigned)(s[u] & 255) << 17) | (unsigned)d[u];
        bkid[p] = (unsigned short)b;
      }
    __syncthreads();
    for (int b = t; b < NB; b += 1024) {
      const int len = off[b + 1] - off[b];
      if (len > 0) {
        const int gb = atomicAdd(&bcur[b], len);
        delta[b] = gb - off[b];
      }
    }
    __syncthreads();
    const int n = off[NB];
    for (int i = t; i < n; i += 1024) {
      const int b = bkid[i];
      const int pos = delta[b] + i;
      if (pos < (b + 1) * CAP) stage[pos] = sorted[i];  // overflow clamp (never hit)
    }
  }
}

// ---------------- kernel 3: per-bucket LDS hist/scan + weight + padded place ------
// CSR region per bucket is fixed: [b*PCAP, (b+1)*PCAP). Each node's run is padded
// to a multiple of 8 with {w=0, dst=first dst of run} so aggr has no bounds logic.
// entry = (bf15(exp2(leaky(ssrc[s]+sdst[d])))<<17) | dst   (w>0 -> 15 bits suffice)
__global__ __launch_bounds__(256) void place2_k(const unsigned* __restrict__ stage,
                                                const int* __restrict__ bcur,
                                                const float* __restrict__ ssrc,
                                                const float* __restrict__ sdst,
                                                unsigned* __restrict__ csrw,
                                                uint2* __restrict__ rc) {
  __shared__ unsigned ebuf[CAP];   // 32 KB
  __shared__ float sl[256];
  __shared__ int hist2[256];
  __shared__ int exc[256];
  __shared__ int cur2[256];
  __shared__ unsigned firstd[256];
  const int b = blockIdx.x;
  const int t = threadIdx.x;
  const int node = b * 256 + t;
  const int base = b * PCAP;
  int tot = bcur[b] - b * CAP;
  tot = tot > CAP ? CAP : tot;
  hist2[t] = 0;
  sl[t] = (node < NN) ? ssrc[node] : 0.f;
  for (int i = t; i < tot; i += 256) ebuf[i] = stage[(size_t)b * CAP + i];
  __syncthreads();
  for (int i = t; i < tot; i += 256) atomicAdd(&hist2[ebuf[i] >> 17], 1);
  __syncthreads();
  // exclusive scan of PADDED counts by wave 0 (4/lane)
  if (t < 64) {
    int p[4];
    int sum = 0;
#pragma unroll
    for (int i = 0; i < 4; ++i) {
      const int c = hist2[t * 4 + i];
      p[i] = (c + 7) & ~7;  // 0 stays 0
      sum += p[i];
    }
    int pre = sum;
#pragma unroll
    for (int o = 1; o < 64; o <<= 1) {
      const int nb = __shfl_up(pre, o, 64);
      if (t >= o) pre += nb;
    }
    pre -= sum;
    int run = pre;
#pragma unroll
    for (int i = 0; i < 4; ++i) { exc[t * 4 + i] = run; run += p[i]; }
  }
  __syncthreads();
  const int c = hist2[t];
  const int pc = (c + 7) & ~7;
  if (node < NN) rc[node] = make_uint2((unsigned)pc, (unsigned)(base + exc[t]));
  cur2[t] = exc[t];
  __syncthreads();
  for (int i = t; i < tot; i += 256) {
    const unsigned u = ebuf[i];
    const int s = u >> 17;
    const unsigned d = u & 0x1ffffu;
    const float sv = sl[s] + sdst[d];                 // log2-domain score
    const float w = exp2f(fmaxf(sv, 0.2f * sv));      // leaky+exp, w > 0
    unsigned wb = __builtin_bit_cast(unsigned, w);
    wb += 0x7fffu + ((wb >> 16) & 1u);                // round-to-nearest bf16
    const unsigned ent = ((wb >> 16) << 17) | d;      // sign bit is 0 -> 15 bits
    const int p = atomicAdd(&cur2[s], 1);
    if (p == exc[s]) firstd[s] = d;                   // capture a hot pad target
    csrw[base + p] = ent;
  }
  __syncthreads();
  // pad each run to multiple of 8 with {w=0, dst=firstd} (row stays L1/L2-hot)
  if (c > 0) {
    const unsigned padent = firstd[t];                // weight bits = 0 -> w = 0.0f
    const int e0 = exc[t];
    for (int i = c; i < pc; ++i) csrw[base + e0 + i] = padent;
  }
}

// ---------------- kernel 4: wave-per-node aggregate, dot2 inner loop --------------
// lane-group g = lane>>4 handles edge slot g; lane sub = lane&15 covers cols sub*8..+7
__global__ __launch_bounds__(256) void aggr_k(
    const unsigned short* __restrict__ h, const unsigned* __restrict__ csrw,
    const uint2* __restrict__ rc, float* __restrict__ out) {
  const int lane = threadIdx.x & 63;
  const int g = lane >> 4;
  const int sub = lane & 15;
  const int node = blockIdx.x * 4 + (threadIdx.x >> 6);  // grid covers exactly NN
  const uint2 rcv = rc[node];
  const int pdeg = (int)rcv.x;                 // padded degree (multiple of 8)
  const int r0 = (int)rcv.y;
  const uint4* __restrict__ hp = (const uint4*)h;  // one h row = 16 uint4
  float acc[8] = {0.f, 0.f, 0.f, 0.f, 0.f, 0.f, 0.f, 0.f};
  float sw = 0.f;
  const unsigned losel = 0x05040100u;   // [e0.lo16 | e1.lo16]
  const unsigned hisel = 0x07060302u;   // [e0.hi16 | e1.hi16]
  const unsigned onepk = 0x3F803F80u;   // packed bf16 (1.0, 1.0)
  const int nit = pdeg >> 3;  // 8 edges per iteration (4 groups x 2 slots)
  if (nit > 0) {
    int j = r0 + g;
    unsigned uA0 = csrw[j];
    unsigned uA1 = csrw[j + 4];
    uint4 pA0 = hp[(uA0 & 0x1ffffu) * 16u + sub];
    uint4 pA1 = hp[(uA1 & 0x1ffffu) * 16u + sub];
    for (int it = 0; it < nit; ++it) {
      unsigned uB0, uB1;
      uint4 pB0, pB1;
      const bool more = (it + 1) < nit;
      if (more) {
        j += 8;
        uB0 = csrw[j];
        uB1 = csrw[j + 4];
        pB0 = hp[(uB0 & 0x1ffffu) * 16u + sub];
        pB1 = hp[(uB1 & 0x1ffffu) * 16u + sub];
      }
      const unsigned wpk = (uA0 >> 17) | ((uA1 >> 17) << 16);  // bf16 pair (w0,w1)
      asm("v_dot2_f32_bf16 %0, %1, %2, %0" : "+v"(sw) : "v"(wpk), "v"(onepk));
      const unsigned k0a[4] = {pA0.x, pA0.y, pA0.z, pA0.w};
      const unsigned k1a[4] = {pA1.x, pA1.y, pA1.z, pA1.w};
#pragma unroll
      for (int q = 0; q < 4; ++q) {
        const unsigned lo = __builtin_amdgcn_perm(k1a[q], k0a[q], losel);
        const unsigned hi = __builtin_amdgcn_perm(k1a[q], k0a[q], hisel);
        asm("v_dot2_f32_bf16 %0, %1, %2, %0" : "+v"(acc[q * 2]) : "v"(wpk), "v"(lo));
        asm("v_dot2_f32_bf16 %0, %1, %2, %0" : "+v"(acc[q * 2 + 1]) : "v"(wpk), "v"(hi));
      }
      if (more) { uA0 = uB0; uA1 = uB1; pA0 = pB0; pA1 = pB1; }
    }
  }
  // reduce across the 4 edge-groups (same sub = same columns)
#pragma unroll
  for (int off = 16; off < 64; off <<= 1) {
    sw += __shfl_xor(sw, off, 64);
#pragma unroll
    for (int q = 0; q < 8; ++q) acc[q] += __shfl_xor(acc[q], off, 64);
  }
  const float inv = pdeg > 0 ? 1.0f / sw : 0.f;
  float o[8];
#pragma unroll
  for (int q = 0; q < 8; ++q) {
    const float v = acc[q] * inv;
    o[q] = v > 0.f ? v : __expf(v) - 1.f;  // elu alpha=1
  }
  if (lane < 16) {
    float4* op = (float4*)(out + (size_t)node * OD + sub * 8);
    op[0] = make_float4(o[0], o[1], o[2], o[3]);
    op[1] = make_float4(o[4], o[5], o[6], o[7]);
  }
}

extern "C" void kernel_launch(void* const* d_in, const int* in_sizes, int n_in,
                              void* d_out, int out_size, void* d_ws, size_t ws_size,
                              hipStream_t stream) {
  const float* x = (const float*)d_in[0];
  const int* el = (const int*)d_in[1];
  const float* W = (const float*)d_in[2];
  const float* a = (const float*)d_in[3];
  float* out = (float*)d_out;
  char* ws = (char*)d_ws;

  const size_t S = 400384;  // 100000*4 padded to 512
  float* ssrc    = (float*)(ws + 0 * S);
  float* sdst    = (float*)(ws + 1 * S);
  uint2* rc      = (uint2*)(ws + 2 * S);        // 800 KB (spans slots 2+3)
  int* bcur      = (int*)(ws + 4 * S);          // 391 ints
  unsigned short* Wt = (unsigned short*)(ws + 4 * S + 8192);          // 64 KB
  unsigned short* h  = (unsigned short*)(ws + 4 * S + 8192 + 65536);  // 25.6 MB
  unsigned* csrw = (unsigned*)(ws + 4 * S + 8192 + 65536 + (size_t)NN * OD * 2);  // 15.6 MB
  // staging (12.81 MB) lives in d_out scratch space (51.2 MB); consumed by
  // place2_k before aggr_k rewrites every output element.
  unsigned* stage = (unsigned*)d_out;

  prep_wt_k<<<128, 256, 0, stream>>>(W, Wt, bcur);
  fused_k<<<NGB + NBIN, 1024, 0, stream>>>(x, Wt, a, h, ssrc, sdst, el, bcur, stage);
  place2_k<<<NB, 256, 0, stream>>>(stage, bcur, ssrc, sdst, csrw, rc);
  aggr_k<<<NN / 4, 256, 0, stream>>>(h, csrw, rc, out);
}

// Round 17
// 116.813 us; speedup vs baseline: 1.8816x; 1.0002x over previous
//
#include <hip/hip_runtime.h>
#include <hip/hip_bf16.h>
#include <cstdint>
#include <cstddef>

#define NN 100000
#define NE 1600000
#define KD 256
#define OD 128
#define NB 391      // ceil(NN/256) buckets of 256 src nodes (place/aggr CSR)
#define CAP 8192    // staging capacity per bucket (mean 6250, sigma ~79)
#define PCAP 9984   // padded CSR region per bucket (CAP + 256*7)
#define NGB 391     // gemm blocks in fused kernel (256 rows each, 1024 thr)
#define NBIN 121    // bin blocks; grid-stride over 391 batches of 4096 edges
#define NBATCH 391  // edge batches (391*4096 >= 1.6M)

typedef __attribute__((ext_vector_type(8))) __bf16 bf16x8;
typedef __attribute__((ext_vector_type(4))) float f32x4;
typedef __attribute__((ext_vector_type(8))) unsigned short ushort8;

static __device__ __forceinline__ unsigned short f2bf(float f) {
  return __builtin_bit_cast(unsigned short, (__bf16)f);
}

// ---------------- kernel 1: W -> Wt bf16 transposed; also init bcur ---------------
__global__ void prep_wt_k(const float* __restrict__ W, unsigned short* __restrict__ Wt,
                          int* __restrict__ bcur) {
  const int i = blockIdx.x * 256 + threadIdx.x;  // 32768 total
  const int k = i >> 7;   // 0..255
  const int n = i & 127;  // 0..127
  Wt[n * KD + k] = f2bf(W[i]);
  if (i < NB) bcur[i] = i * CAP;
}

// ---------------- kernel 2: FUSED  gemm (blocks 0..390) | bin (391..511) ----------
// Grid = EXACTLY 512 blocks = 256 CU x 2 blocks/CU -> zero dispatch tail (R16's
// 782-block grid ran 1.53 scheduling rounds; second round used half the machine).
// gemm: 1024 thr = 16 waves, 256 rows/block, whole Wt in LDS (XOR-swizzled).
// bin : 121 blocks grid-striding 391 batches of 4096 edges (LDS sort per batch).
__global__ __launch_bounds__(1024, 8) void fused_k(
    const float* __restrict__ x, const unsigned short* __restrict__ Wt,
    const float* __restrict__ a, unsigned short* __restrict__ h,
    float* __restrict__ ssrc, float* __restrict__ sdst,
    const int* __restrict__ el, int* __restrict__ bcur,
    unsigned* __restrict__ stage) {
  __shared__ alignas(16) char smem[65536];
  const int t = threadIdx.x;

  if (blockIdx.x < NGB) {
    // ------------------------- GEMM part -------------------------
    unsigned short* Bl = (unsigned short*)smem;  // 128 rows x 512 B, swizzled
#pragma unroll
    for (int it = 0; it < 4; ++it) {
      const int c = it * 1024 + t;       // 4096 chunks of 16 B
      const int r = c >> 5;
      const int c16 = c & 31;
      const ushort8 v = *(const ushort8*)(Wt + r * 256 + c16 * 8);
      const int byt = (r * 512 + c16 * 16) ^ ((r & 7) << 4);
      *(ushort8*)((char*)Bl + byt) = v;
    }
    const int lane = t & 63;
    const int wave = t >> 6;             // 0..15
    const int col = lane & 15;
    const int kg = lane >> 4;
    const int m0 = blockIdx.x * 256 + wave * 16;
    const int arow = m0 + col;
    const bool rowok = arow < NN;
    const float* __restrict__ xrow = x + (size_t)arow * KD;
    __syncthreads();

    f32x4 acc[8];
#pragma unroll
    for (int i = 0; i < 8; ++i) acc[i] = (f32x4)0.0f;

#pragma unroll
    for (int s = 0; s < 8; ++s) {
      const int kk = s * 32 + kg * 8;
      bf16x8 af = (bf16x8)(__bf16)0.0f;
      if (rowok) {
        const float4 f0 = *(const float4*)(xrow + kk);
        const float4 f1 = *(const float4*)(xrow + kk + 4);
        af[0] = (__bf16)f0.x; af[1] = (__bf16)f0.y; af[2] = (__bf16)f0.z; af[3] = (__bf16)f0.w;
        af[4] = (__bf16)f1.x; af[5] = (__bf16)f1.y; af[6] = (__bf16)f1.z; af[7] = (__bf16)f1.w;
      }
#pragma unroll
      for (int nt = 0; nt < 8; ++nt) {
        const int n = nt * 16 + col;
        const int byt = (n * 512 + s * 64 + kg * 16) ^ ((col & 7) << 4);
        const ushort8 bu = *(const ushort8*)((const char*)Bl + byt);
        const bf16x8 bf = __builtin_bit_cast(bf16x8, bu);
        acc[nt] = __builtin_amdgcn_mfma_f32_16x16x32_bf16(af, bf, acc[nt], 0, 0, 0);
      }
    }

    // C/D layout: col = lane&15, row = (lane>>4)*4 + r
    float ps[4] = {0.f, 0.f, 0.f, 0.f};
    float pd[4] = {0.f, 0.f, 0.f, 0.f};
#pragma unroll
    for (int nt = 0; nt < 8; ++nt) {
      const int n = nt * 16 + col;
      const float av = a[n];
      const float av2 = a[OD + n];
#pragma unroll
      for (int r = 0; r < 4; ++r) {
        const float v = acc[nt][r];
        const int row = m0 + kg * 4 + r;
        if (row < NN) h[(size_t)row * OD + n] = f2bf(v);
        ps[r] += v * av;
        pd[r] += v * av2;
      }
    }
#pragma unroll
    for (int off = 1; off < 16; off <<= 1) {
#pragma unroll
      for (int r = 0; r < 4; ++r) {
        ps[r] += __shfl_xor(ps[r], off, 64);
        pd[r] += __shfl_xor(pd[r], off, 64);
      }
    }
    if (col == 0) {
#pragma unroll
      for (int r = 0; r < 4; ++r) {
        const int row = m0 + kg * 4 + r;
        // pre-scale scores by log2(e): weight pass uses exp2 (leaky commutes w/ scale)
        if (row < NN) {
          ssrc[row] = ps[r] * 1.442695041f;
          sdst[row] = pd[r] * 1.442695041f;
        }
      }
    }
  } else {
    // ------------------------- BIN part -------------------------
    unsigned* sorted = (unsigned*)smem;                       // 16384 B
    unsigned short* bkid = (unsigned short*)(smem + 16384);   // 8192 B
    int* hist  = (int*)(smem + 24576);                        // 392*4
    int* off   = (int*)(smem + 26144);                        // 392*4
    int* cur   = (int*)(smem + 27712);                        // 391*4
    int* delta = (int*)(smem + 29276);                        // 391*4
    for (int batch = (int)blockIdx.x - NGB; batch < NBATCH; batch += NBIN) {
      __syncthreads();  // protect LDS reuse across batches (no-op first pass)
      const int te = batch * 4096 + t * 4;
      int s[4], d[4];
      bool valid[4];
#pragma unroll
      for (int u = 0; u < 4; ++u) valid[u] = (te + u) < NE;
      if (te + 3 < NE) {
        const int4 a0 = *(const int4*)(el + te);
        const int4 b0 = *(const int4*)(el + NE + te);
        s[0] = a0.x; s[1] = a0.y; s[2] = a0.z; s[3] = a0.w;
        d[0] = b0.x; d[1] = b0.y; d[2] = b0.z; d[3] = b0.w;
      } else {
#pragma unroll
        for (int u = 0; u < 4; ++u) {
          s[u] = valid[u] ? el[te + u] : 0;
          d[u] = valid[u] ? el[NE + te + u] : 0;
        }
      }
      for (int i = t; i <= NB; i += 1024) hist[i] = 0;
      __syncthreads();
#pragma unroll
      for (int u = 0; u < 4; ++u)
        if (valid[u]) atomicAdd(&hist[s[u] >> 8], 1);
      __syncthreads();
      // exclusive scan of hist[0..NB] by wave 0 (7 entries/lane)
      if (t < 64) {
        int v[7];
        int sum = 0;
#pragma unroll
        for (int i = 0; i < 7; ++i) {
          const int idx = t * 7 + i;
          v[i] = (idx <= NB) ? hist[idx] : 0;
          sum += v[i];
        }
        int pre = sum;
#pragma unroll
        for (int o = 1; o < 64; o <<= 1) {
          const int nb = __shfl_up(pre, o, 64);
          if (t >= o) pre += nb;
        }
        pre -= sum;  // exclusive across lanes
        int run = pre;
#pragma unroll
        for (int i = 0; i < 7; ++i) {
          const int idx = t * 7 + i;
          if (idx <= NB) off[idx] = run;
          run += v[i];
        }
      }
      __syncthreads();
      for (int i = t; i < NB; i += 1024) cur[i] = off[i];
      __syncthreads();
#pragma unroll
      for (int u = 0; u < 4; ++u)
        if (valid[u]) {
          const int b = s[u] >> 8;
          const int p = atomicAdd(&cur[b], 1);
          sorted[p] = ((unsigned)(s[u] & 255) << 17) | (unsigned)d[u];
          bkid[p] = (unsigned short)b;
        }
      __syncthreads();
      for (int b = t; b < NB; b += 1024) {
        const int len = off[b + 1] - off[b];
        if (len > 0) {
          const int gb = atomicAdd(&bcur[b], len);
          delta[b] = gb - off[b];
        }
      }
      __syncthreads();
      const int n = off[NB];
      for (int i = t; i < n; i += 1024) {
        const int b = bkid[i];
        const int pos = delta[b] + i;
        if (pos < (b + 1) * CAP) stage[pos] = sorted[i];  // overflow clamp (never hit)
      }
    }
  }
}

// ---------------- kernel 3: per-bucket LDS hist/scan + weight + padded place ------
// CSR region per bucket is fixed: [b*PCAP, (b+1)*PCAP). Each node's run is padded
// to a multiple of 8 with {w=0, dst=first dst of run} so aggr has no bounds logic.
// entry = (bf15(exp2(leaky(ssrc[s]+sdst[d])))<<17) | dst   (w>0 -> 15 bits suffice)
__global__ __launch_bounds__(256) void place2_k(const unsigned* __restrict__ stage,
                                                const int* __restrict__ bcur,
                                                const float* __restrict__ ssrc,
                                                const float* __restrict__ sdst,
                                                unsigned* __restrict__ csrw,
                                                uint2* __restrict__ rc) {
  __shared__ unsigned ebuf[CAP];   // 32 KB
  __shared__ float sl[256];
  __shared__ int hist2[256];
  __shared__ int exc[256];
  __shared__ int cur2[256];
  __shared__ unsigned firstd[256];
  const int b = blockIdx.x;
  const int t = threadIdx.x;
  const int node = b * 256 + t;
  const int base = b * PCAP;
  int tot = bcur[b] - b * CAP;
  tot = tot > CAP ? CAP : tot;
  hist2[t] = 0;
  sl[t] = (node < NN) ? ssrc[node] : 0.f;
  for (int i = t; i < tot; i += 256) ebuf[i] = stage[(size_t)b * CAP + i];
  __syncthreads();
  for (int i = t; i < tot; i += 256) atomicAdd(&hist2[ebuf[i] >> 17], 1);
  __syncthreads();
  // exclusive scan of PADDED counts by wave 0 (4/lane)
  if (t < 64) {
    int p[4];
    int sum = 0;
#pragma unroll
    for (int i = 0; i < 4; ++i) {
      const int c = hist2[t * 4 + i];
      p[i] = (c + 7) & ~7;  // 0 stays 0
      sum += p[i];
    }
    int pre = sum;
#pragma unroll
    for (int o = 1; o < 64; o <<= 1) {
      const int nb = __shfl_up(pre, o, 64);
      if (t >= o) pre += nb;
    }
    pre -= sum;
    int run = pre;
#pragma unroll
    for (int i = 0; i < 4; ++i) { exc[t * 4 + i] = run; run += p[i]; }
  }
  __syncthreads();
  const int c = hist2[t];
  const int pc = (c + 7) & ~7;
  if (node < NN) rc[node] = make_uint2((unsigned)pc, (unsigned)(base + exc[t]));
  cur2[t] = exc[t];
  __syncthreads();
  for (int i = t; i < tot; i += 256) {
    const unsigned u = ebuf[i];
    const int s = u >> 17;
    const unsigned d = u & 0x1ffffu;
    const float sv = sl[s] + sdst[d];                 // log2-domain score
    const float w = exp2f(fmaxf(sv, 0.2f * sv));      // leaky+exp, w > 0
    unsigned wb = __builtin_bit_cast(unsigned, w);
    wb += 0x7fffu + ((wb >> 16) & 1u);                // round-to-nearest bf16
    const unsigned ent = ((wb >> 16) << 17) | d;      // sign bit is 0 -> 15 bits
    const int p = atomicAdd(&cur2[s], 1);
    if (p == exc[s]) firstd[s] = d;                   // capture a hot pad target
    csrw[base + p] = ent;
  }
  __syncthreads();
  // pad each run to multiple of 8 with {w=0, dst=firstd} (row stays L1/L2-hot)
  if (c > 0) {
    const unsigned padent = firstd[t];                // weight bits = 0 -> w = 0.0f
    const int e0 = exc[t];
    for (int i = c; i < pc; ++i) csrw[base + e0 + i] = padent;
  }
}

// ---------------- kernel 4: wave-per-node aggregate, dot2 inner loop --------------
// lane-group g = lane>>4 handles edge slot g; lane sub = lane&15 covers cols sub*8..+7
__global__ __launch_bounds__(256) void aggr_k(
    const unsigned short* __restrict__ h, const unsigned* __restrict__ csrw,
    const uint2* __restrict__ rc, float* __restrict__ out) {
  const int lane = threadIdx.x & 63;
  const int g = lane >> 4;
  const int sub = lane & 15;
  const int node = blockIdx.x * 4 + (threadIdx.x >> 6);  // grid covers exactly NN
  const uint2 rcv = rc[node];
  const int pdeg = (int)rcv.x;                 // padded degree (multiple of 8)
  const int r0 = (int)rcv.y;
  const uint4* __restrict__ hp = (const uint4*)h;  // one h row = 16 uint4
  float acc[8] = {0.f, 0.f, 0.f, 0.f, 0.f, 0.f, 0.f, 0.f};
  float sw = 0.f;
  const unsigned losel = 0x05040100u;   // [e0.lo16 | e1.lo16]
  const unsigned hisel = 0x07060302u;   // [e0.hi16 | e1.hi16]
  const unsigned onepk = 0x3F803F80u;   // packed bf16 (1.0, 1.0)
  const int nit = pdeg >> 3;  // 8 edges per iteration (4 groups x 2 slots)
  if (nit > 0) {
    int j = r0 + g;
    unsigned uA0 = csrw[j];
    unsigned uA1 = csrw[j + 4];
    uint4 pA0 = hp[(uA0 & 0x1ffffu) * 16u + sub];
    uint4 pA1 = hp[(uA1 & 0x1ffffu) * 16u + sub];
    for (int it = 0; it < nit; ++it) {
      unsigned uB0, uB1;
      uint4 pB0, pB1;
      const bool more = (it + 1) < nit;
      if (more) {
        j += 8;
        uB0 = csrw[j];
        uB1 = csrw[j + 4];
        pB0 = hp[(uB0 & 0x1ffffu) * 16u + sub];
        pB1 = hp[(uB1 & 0x1ffffu) * 16u + sub];
      }
      const unsigned wpk = (uA0 >> 17) | ((uA1 >> 17) << 16);  // bf16 pair (w0,w1)
      asm("v_dot2_f32_bf16 %0, %1, %2, %0" : "+v"(sw) : "v"(wpk), "v"(onepk));
      const unsigned k0a[4] = {pA0.x, pA0.y, pA0.z, pA0.w};
      const unsigned k1a[4] = {pA1.x, pA1.y, pA1.z, pA1.w};
#pragma unroll
      for (int q = 0; q < 4; ++q) {
        const unsigned lo = __builtin_amdgcn_perm(k1a[q], k0a[q], losel);
        const unsigned hi = __builtin_amdgcn_perm(k1a[q], k0a[q], hisel);
        asm("v_dot2_f32_bf16 %0, %1, %2, %0" : "+v"(acc[q * 2]) : "v"(wpk), "v"(lo));
        asm("v_dot2_f32_bf16 %0, %1, %2, %0" : "+v"(acc[q * 2 + 1]) : "v"(wpk), "v"(hi));
      }
      if (more) { uA0 = uB0; uA1 = uB1; pA0 = pB0; pA1 = pB1; }
    }
  }
  // reduce across the 4 edge-groups (same sub = same columns)
#pragma unroll
  for (int off = 16; off < 64; off <<= 1) {
    sw += __shfl_xor(sw, off, 64);
#pragma unroll
    for (int q = 0; q < 8; ++q) acc[q] += __shfl_xor(acc[q], off, 64);
  }
  const float inv = pdeg > 0 ? 1.0f / sw : 0.f;
  float o[8];
#pragma unroll
  for (int q = 0; q < 8; ++q) {
    const float v = acc[q] * inv;
    o[q] = v > 0.f ? v : __expf(v) - 1.f;  // elu alpha=1
  }
  if (lane < 16) {
    float4* op = (float4*)(out + (size_t)node * OD + sub * 8);
    op[0] = make_float4(o[0], o[1], o[2], o[3]);
    op[1] = make_float4(o[4], o[5], o[6], o[7]);
  }
}

extern "C" void kernel_launch(void* const* d_in, const int* in_sizes, int n_in,
                              void* d_out, int out_size, void* d_ws, size_t ws_size,
                              hipStream_t stream) {
  const float* x = (const float*)d_in[0];
  const int* el = (const int*)d_in[1];
  const float* W = (const float*)d_in[2];
  const float* a = (const float*)d_in[3];
  float* out = (float*)d_out;
  char* ws = (char*)d_ws;

  const size_t S = 400384;  // 100000*4 padded to 512
  float* ssrc    = (float*)(ws + 0 * S);
  float* sdst    = (float*)(ws + 1 * S);
  uint2* rc      = (uint2*)(ws + 2 * S);        // 800 KB (spans slots 2+3)
  int* bcur      = (int*)(ws + 4 * S);          // 391 ints
  unsigned short* Wt = (unsigned short*)(ws + 4 * S + 8192);          // 64 KB
  unsigned short* h  = (unsigned short*)(ws + 4 * S + 8192 + 65536);  // 25.6 MB
  unsigned* csrw = (unsigned*)(ws + 4 * S + 8192 + 65536 + (size_t)NN * OD * 2);  // 15.6 MB
  // staging (12.81 MB) lives in d_out scratch space (51.2 MB); consumed by
  // place2_k before aggr_k rewrites every output element.
  unsigned* stage = (unsigned*)d_out;

  prep_wt_k<<<128, 256, 0, stream>>>(W, Wt, bcur);
  fused_k<<<NGB + NBIN, 1024, 0, stream>>>(x, Wt, a, h, ssrc, sdst, el, bcur, stage);
  place2_k<<<NB, 256, 0, stream>>>(stage, bcur, ssrc, sdst, csrw, rc);
  aggr_k<<<NN / 4, 256, 0, stream>>>(h, csrw, rc, out);
}